// Round 13
// baseline (192.516 us; speedup 1.0000x reference)
//
// CAM+SE module, MI355X gfx950.
// R13: k3 ported to the R12-proven 256^2 8-phase skeleton: no symmetry
// (4 tiles x 16 b x splitK4 = 256 blocks exactly, no mirror pass), B-panel
// XOR-swizzled row-major (CB-half-separable), A-panel k-slab layout
// [ks][g][row] (ks-half-separable, plain b128 reads). k1/k2/k4/k5 = R12.
#include <hip/hip_runtime.h>
#include <cstdint>
#include <cstddef>

#define B_ 16
#define C_ 512
#define N_ 4096   // H*W
#define CH_ 64    // C/8

#define VMWAIT(n) asm volatile("s_waitcnt vmcnt(" #n ")" ::: "memory")
#define LGKM0()   asm volatile("s_waitcnt lgkmcnt(0)" ::: "memory")
#define BARRAW()  asm volatile("s_barrier" ::: "memory")
#define SCHEDBAR() __builtin_amdgcn_sched_barrier(0)

typedef __attribute__((ext_vector_type(8))) short short8;
typedef __attribute__((ext_vector_type(4))) short short4t;
typedef __attribute__((ext_vector_type(4))) float f32x4;

__device__ __forceinline__ unsigned short f2bf(float f) {
  union { float f; unsigned u; } v; v.f = f;
  unsigned r = v.u + 0x7FFFu + ((v.u >> 16) & 1u);   // RNE
  return (unsigned short)(r >> 16);
}
__device__ __forceinline__ float bf2f(unsigned short u) {
  union { unsigned u; float f; } v; v.u = ((unsigned)u) << 16;
  return v.f;
}
__device__ __forceinline__ ushort4 cvt4(float4 v) {
  ushort4 u; u.x = f2bf(v.x); u.y = f2bf(v.y); u.z = f2bf(v.z); u.w = f2bf(v.w);
  return u;
}
__device__ __forceinline__ void gload_lds16(const void* g, void* l) {
  __builtin_amdgcn_global_load_lds((__attribute__((address_space(1))) void*)g,
                                   (__attribute__((address_space(3))) void*)l,
                                   16, 0, 0);
}
__device__ __forceinline__ unsigned lds_off(const void* p) {
  return (unsigned)(size_t)(__attribute__((address_space(3))) const char*)p;
}

// ================= shared 8-phase staging helpers =================
// Row-major 128-row half, 128B rows, XOR-swizzled source (rule 21).
// STRIDE = source row stride (elements). 2 loads/thread.
template <int STRIDE>
__device__ __forceinline__ void stage_rows_half(
    const unsigned short* __restrict__ src, char* dst, int t, int ko, int h) {
  const int l = t & 63, wid = t >> 6;
  const int srow = l >> 3, scc = l & 7;
#pragma unroll
  for (int i = 0; i < 2; ++i) {
    const int chunk = h * 16 + wid * 2 + i;
    const int row = chunk * 8 + srow;
    const int cc = scc ^ (row & 7);
    gload_lds16(src + (size_t)row * STRIDE + ko + cc * 8, dst + chunk * 1024);
  }
}
// bf b128 reads for (ks, c-half CB): 2 c-frags of this wave's c-quarter.
template <int KS, int CB>
__device__ __forceinline__ void load_bf(const char* Pc, int l, int wc,
                                        short8 (&bf)[2]) {
#pragma unroll
  for (int cf = 0; cf < 2; ++cf) {
    const int c_l = CB * 128 + wc * 32 + cf * 16 + (l & 15);
    bf[cf] = *(const short8*)(Pc + c_l * 128 +
                              (((KS * 4 + (l >> 4)) ^ (c_l & 7)) * 16));
  }
}

// ================= k3 A-panel: k-slab layout =================
// elem (row r, k = h*32 + g*8 + e) at byte h*16384 + g*4096 + r*16 + e*2.
// ks-half h is a linear 16KB slab -> phase-separable; reads conflict-free.
__device__ __forceinline__ void stage_a_half(
    const unsigned short* __restrict__ src,   // qb + d0*N_
    char* dst, int t, int ko, int h) {
  const int r = t & 255;
  const int gb = t >> 8;
#pragma unroll
  for (int i = 0; i < 2; ++i) {
    const int g = gb + 2 * i;
    gload_lds16(src + (size_t)r * N_ + ko + h * 32 + g * 8,
                dst + h * 16384 + g * 4096 + r * 16);
  }
}
// af reads for ks-half KS: 8 d-frags of this wave's d-half. Ordinary b128.
template <int KS>
__device__ __forceinline__ void load_af3(const char* A, int l, int wd2,
                                         short8 (&af)[8]) {
  const char* base = A + KS * 16384 + (l >> 4) * 4096 +
                     (wd2 * 128 + (l & 15)) * 16;
#pragma unroll
  for (int nf = 0; nf < 8; ++nf)
    af[nf] = *(const short8*)(base + nf * 256);   // +16 rows * 16B
}
template <int CB>
__device__ __forceinline__ void mfma16(const short8 (&af)[8], const short8 (&bf)[2],
                                       f32x4 (&acc)[8][4]) {
  __builtin_amdgcn_s_setprio(1);
#pragma unroll
  for (int nf = 0; nf < 8; ++nf)
#pragma unroll
    for (int cf = 0; cf < 2; ++cf)
      acc[nf][CB * 2 + cf] = __builtin_amdgcn_mfma_f32_16x16x32_bf16(
          af[nf], bf[cf], acc[nf][CB * 2 + cf], 0, 0, 0);
  __builtin_amdgcn_s_setprio(0);
}

// ================= k5 q-panel tr-subtile staging (R12) =================
__device__ __forceinline__ void stage_q_half(
    const unsigned short* __restrict__ src, char* dst, int t, int h) {
  const int l = t & 63, wid = t >> 6;
  const int dd = (l >> 1) & 3;
  const int nb = (l >> 3) * 16 + (l & 1) * 8;
#pragma unroll
  for (int i = 0; i < 2; ++i) {
    const int chunk = h * 16 + wid * 2 + i;
    gload_lds16(src + (size_t)((chunk >> 1) * 4 + dd) * N_ + (chunk & 1) * 128 + nb,
                dst + chunk * 1024);
  }
}
template <int KS>
__device__ __forceinline__ void load_af(const char* Qc, int l, int wn2,
                                        short4t (&lo)[8], short4t (&hi)[8]) {
  const unsigned base = lds_off(Qc) + KS * 16384 + (unsigned)((l >> 4) * 4096 +
                        wn2 * 1024 + (l & 15) * 2);
#pragma unroll
  for (int nf = 0; nf < 8; ++nf) {
    const unsigned a = base + nf * 128;
    asm volatile("ds_read_b64_tr_b16 %0, %2\n\t"
                 "ds_read_b64_tr_b16 %1, %2 offset:2048"
                 : "=&v"(lo[nf]), "=&v"(hi[nf]) : "v"(a));
  }
}

// ---------------------------------------------------------------- K1:
__global__ __launch_bounds__(256) void k1_convert(
    const float* __restrict__ x, unsigned short* __restrict__ qbf,
    float* __restrict__ partial) {
  __shared__ float wsum[4];
  const size_t base = (size_t)blockIdx.x * N_;
  const int t = threadIdx.x;
  float s = 0.f;
#pragma unroll
  for (int k = 0; k < 4; ++k) {
    const int idx = (t + k * 256) * 4;
    float4 v = *(const float4*)(x + base + idx);
    *(ushort4*)(qbf + base + idx) = cvt4(v);
    s += (v.x + v.y) + (v.z + v.w);
  }
#pragma unroll
  for (int o = 1; o < 64; o <<= 1) s += __shfl_xor(s, o);
  if ((t & 63) == 0) wsum[t >> 6] = s;
  __syncthreads();
  if (t == 0) partial[blockIdx.x] = (wsum[0] + wsum[1]) + (wsum[2] + wsum[3]);
}

// ---------------------------------------------------------------- K2: SE MLP
__global__ __launch_bounds__(256) void k2_se(
    const float* __restrict__ partial, const float* __restrict__ gamma,
    const float* __restrict__ W1, const float* __restrict__ b1,
    const float* __restrict__ W2, const float* __restrict__ b2,
    float* __restrict__ gse) {
  __shared__ float se_s[C_];
  __shared__ float hp[4][CH_];
  __shared__ float h_s[CH_];
  const int b = blockIdx.x, t = threadIdx.x;
  for (int c = t; c < C_; c += 256)
    se_s[c] = partial[b * C_ + c] * (1.0f / (float)N_);
  __syncthreads();
  {
    const int h = t & 63, seg = t >> 6;
    float a = 0.f;
    const int cb = seg * 128;
    for (int c = cb; c < cb + 128; ++c) a += se_s[c] * W1[c * CH_ + h];
    hp[seg][h] = a;
  }
  __syncthreads();
  if (t < CH_) {
    float a = b1[t] + hp[0][t] + hp[1][t] + hp[2][t] + hp[3][t];
    h_s[t] = fmaxf(a, 0.f);
  }
  __syncthreads();
  const float g = gamma[0];
  for (int c = t; c < C_; c += 256) {
    float a = b2[c];
#pragma unroll
    for (int hh = 0; hh < CH_; ++hh) a += h_s[hh] * W2[hh * C_ + c];
    const float sig = 1.0f / (1.0f + __expf(-a));
    gse[b * C_ + c] = g * sig;
  }
}

// ---------------------------------------------------------------- K3:
// epartial[kc][b][c][d] = q q^T K-chunk. 256d x 256c tile, 8 waves
// (wd2 d-half x wc c-quarter), 16 kt of BK=64, 8-phase counted schedule.
// A = d-rows (k-slab layout), B = c-rows (swizzled row-major).
__global__ __launch_bounds__(512) void k3_energy(
    const unsigned short* __restrict__ qbf, float* __restrict__ ep) {
  __shared__ alignas(16) char lds[131072];
  const int orig = blockIdx.x;
  const int assign = (orig & 7) * 32 + (orig >> 3);   // 256 = 8 x 32 bijective
  const int b = assign >> 4;                           // 2 batches per XCD
  const int rem = assign & 15;
  const int kc = rem >> 2;
  const int d0 = ((rem >> 1) & 1) * 256, c0 = (rem & 1) * 256;
  const unsigned short* qb = qbf + (size_t)b * C_ * N_ + kc * 1024;
  const unsigned short* ap = qb + (size_t)d0 * N_;   // A panel rows (d)
  const unsigned short* bp = qb + (size_t)c0 * N_;   // B panel rows (c)
  const int t = threadIdx.x, l = t & 63, wid = t >> 6;
  const int wd2 = wid >> 2, wc = wid & 3;
  f32x4 acc[8][4];
#pragma unroll
  for (int m = 0; m < 8; ++m)
#pragma unroll
    for (int n = 0; n < 4; ++n) acc[m][n] = (f32x4){0.f, 0.f, 0.f, 0.f};
  char* P0 = lds;            char* P1 = lds + 32768;    // B dbuf
  char* Q0 = lds + 65536;    char* Q1 = lds + 98304;    // A dbuf

  short8 af[8], bf[2];

  // prologue: issue order B0,B1,A0,A1 (matches in-loop order)
  stage_rows_half<N_>(bp, P0, t, 0, 0);
  stage_rows_half<N_>(bp, P0, t, 0, 1);
  stage_a_half(ap, Q0, t, 0, 0);
  stage_a_half(ap, Q0, t, 0, 1);

  for (int kt = 0; kt < 16; ++kt) {
    const char* Pc = (kt & 1) ? P1 : P0;
    const char* Qc = (kt & 1) ? Q1 : Q0;
    char* Pn = (kt & 1) ? P0 : P1;
    char* Qn = (kt & 1) ? Q0 : Q1;
    const int ko = (kt + 1) * 64;
    // ---- ph1 (ks0, CB0): needs A-full + B-c0 ----
    VMWAIT(2);
    BARRAW();
    load_af3<0>(Qc, l, wd2, af);
    load_bf<0, 0>(Pc, l, wc, bf);
    if (kt < 15) stage_rows_half<N_>(bp, Pn, t, ko, 0);
    LGKM0(); SCHEDBAR();
    mfma16<0>(af, bf, acc);
    // ---- ph2 (ks0, CB1) ----
    load_bf<0, 1>(Pc, l, wc, bf);
    if (kt < 15) stage_rows_half<N_>(bp, Pn, t, ko, 1);
    LGKM0(); SCHEDBAR();
    mfma16<1>(af, bf, acc);
    // ---- ph3 (ks1, CB1): needs A ks-half 1 ----
    if (kt < 15) { VMWAIT(4); } else { VMWAIT(0); }
    BARRAW();
    load_af3<1>(Qc, l, wd2, af);
    load_bf<1, 1>(Pc, l, wc, bf);
    if (kt < 15) stage_a_half(ap, Qn, t, ko, 0);
    LGKM0(); SCHEDBAR();
    mfma16<1>(af, bf, acc);
    // ---- ph4 (ks1, CB0) ----
    load_bf<1, 0>(Pc, l, wc, bf);
    if (kt < 15) stage_a_half(ap, Qn, t, ko, 1);
    LGKM0(); SCHEDBAR();
    mfma16<0>(af, bf, acc);
  }

  // Epilogue: two d-half sweeps; epartial rows = c (d contiguous).
  float* Lf = (float*)lds;
  float* eb = ep + ((size_t)(kc * B_ + b)) * C_ * C_;
  const int g16 = l >> 4;
#pragma unroll
  for (int s = 0; s < 2; ++s) {
    BARRAW();
    if (wd2 == s) {
#pragma unroll
      for (int nf = 0; nf < 8; ++nf)
#pragma unroll
        for (int j = 0; j < 4; ++j) {
          const int c_l = (j >> 1) * 128 + wc * 32 + (j & 1) * 16 + (l & 15);
          const int d4 = nf * 16 + g16 * 4;
          *(float4*)&Lf[c_l * 128 + (d4 ^ ((c_l & 7) << 2))] =
              *(const float4*)&acc[nf][j];
        }
    }
    BARRAW();
#pragma unroll
    for (int it = 0; it < 16; ++it) {
      const int row = it * 16 + (t >> 5);
      const int col4 = (t & 31) * 4;
      float4 v = *(const float4*)&Lf[row * 128 + (col4 ^ ((row & 7) << 2))];
      *(float4*)&eb[(size_t)(c0 + row) * C_ + d0 + s * 128 + col4] = v;
    }
  }
}

// ---------------------------------------------------------------- K4 (R9):
__global__ __launch_bounds__(256) void k4_softmax(const float* __restrict__ ep,
                                                  unsigned short* __restrict__ att) {
  const int t = threadIdx.x, l = t & 63, wid = t >> 6;
  const size_t row = (size_t)blockIdx.x * 4 + wid;
  f32x4 v0 = (f32x4){0.f, 0.f, 0.f, 0.f}, v1 = v0;
#pragma unroll
  for (int k = 0; k < 4; ++k) {
    const f32x4* er = (const f32x4*)(ep + ((size_t)k * B_ * C_ + row) * C_);
    v0 += er[l];
    v1 += er[64 + l];
  }
  float mn = fminf(fminf(fminf(v0[0], v0[1]), fminf(v0[2], v0[3])),
                   fminf(fminf(v1[0], v1[1]), fminf(v1[2], v1[3])));
#pragma unroll
  for (int s = 1; s < 64; s <<= 1) mn = fminf(mn, __shfl_xor(mn, s));
  float e0 = __expf(mn - v0[0]), e1 = __expf(mn - v0[1]);
  float e2 = __expf(mn - v0[2]), e3 = __expf(mn - v0[3]);
  float e4 = __expf(mn - v1[0]), e5 = __expf(mn - v1[1]);
  float e6 = __expf(mn - v1[2]), e7 = __expf(mn - v1[3]);
  float sm = ((e0 + e1) + (e2 + e3)) + ((e4 + e5) + (e6 + e7));
#pragma unroll
  for (int s = 1; s < 64; s <<= 1) sm += __shfl_xor(sm, s);
  const float inv = 1.0f / sm;
  unsigned short* ar = att + row * C_;
  ushort4 u0, u1;
  u0.x = f2bf(e0 * inv); u0.y = f2bf(e1 * inv);
  u0.z = f2bf(e2 * inv); u0.w = f2bf(e3 * inv);
  u1.x = f2bf(e4 * inv); u1.y = f2bf(e5 * inv);
  u1.z = f2bf(e6 * inv); u1.w = f2bf(e7 * inv);
  *(ushort4*)(ar + 4 * l) = u0;
  *(ushort4*)(ar + 256 + 4 * l) = u1;
}

// ---------------------------------------------------------------- K5 (R12):
__global__ __launch_bounds__(512) void k5_pv(
    const unsigned short* __restrict__ att, const unsigned short* __restrict__ qbf,
    const float* __restrict__ gse, float* __restrict__ out) {
  __shared__ alignas(16) char lds[131072];
  const int orig = blockIdx.x;
  const int wg = (orig & 7) * 64 + (orig >> 3);   // 512 = 8 x 64 bijective
  const int b = wg >> 5;                           // 2 batches per XCD
  const int rem = wg & 31;
  const int c0 = (rem & 1) * 256, n0 = (rem >> 1) * 256;
  const int t = threadIdx.x, l = t & 63, wid = t >> 6;
  const int wn2 = wid >> 2, wc = wid & 3;
  const unsigned short* ab = att + (size_t)b * C_ * C_ + (size_t)c0 * C_;
  const unsigned short* qb = qbf + (size_t)b * C_ * N_ + n0;   // + d*N_
  f32x4 acc[8][4];
#pragma unroll
  for (int m = 0; m < 8; ++m)
#pragma unroll
    for (int n = 0; n < 4; ++n) acc[m][n] = (f32x4){0.f, 0.f, 0.f, 0.f};
  char* P0 = lds;            char* P1 = lds + 32768;    // att dbuf
  char* Q0 = lds + 65536;    char* Q1 = lds + 98304;    // q dbuf

  short4t lo[8], hi[8];
  short8 af[8], bf[2];

  stage_rows_half<C_>(ab, P0, t, 0, 0);
  stage_rows_half<C_>(ab, P0, t, 0, 1);
  stage_q_half(qb, Q0, t, 0);
  stage_q_half(qb, Q0, t, 1);

  for (int kt = 0; kt < 8; ++kt) {
    const char* Pc = (kt & 1) ? P1 : P0;
    const char* Qc = (kt & 1) ? Q1 : Q0;
    char* Pn = (kt & 1) ? P0 : P1;
    char* Qn = (kt & 1) ? Q0 : Q1;
    const int ko = (kt + 1) * 64;
    const unsigned short* qn = qb + (size_t)ko * N_;
    // ---- ph1 (ks0, CB0) ----
    VMWAIT(2);
    BARRAW();
    load_af<0>(Qc, l, wn2, lo, hi);
    load_bf<0, 0>(Pc, l, wc, bf);
    if (kt < 7) stage_rows_half<C_>(ab, Pn, t, ko, 0);
    LGKM0(); SCHEDBAR();
#pragma unroll
    for (int nf = 0; nf < 8; ++nf)
      af[nf] = __builtin_shufflevector(lo[nf], hi[nf], 0, 1, 2, 3, 4, 5, 6, 7);
    mfma16<0>(af, bf, acc);
    // ---- ph2 (ks0, CB1) ----
    load_bf<0, 1>(Pc, l, wc, bf);
    if (kt < 7) stage_rows_half<C_>(ab, Pn, t, ko, 1);
    LGKM0(); SCHEDBAR();
    mfma16<1>(af, bf, acc);
    // ---- ph3 (ks1, CB1) ----
    if (kt < 7) { VMWAIT(4); } else { VMWAIT(0); }
    BARRAW();
    load_af<1>(Qc, l, wn2, lo, hi);
    load_bf<1, 1>(Pc, l, wc, bf);
    if (kt < 7) stage_q_half(qn, Qn, t, 0);
    LGKM0(); SCHEDBAR();
#pragma unroll
    for (int nf = 0; nf < 8; ++nf)
      af[nf] = __builtin_shufflevector(lo[nf], hi[nf], 0, 1, 2, 3, 4, 5, 6, 7);
    mfma16<1>(af, bf, acc);
    // ---- ph4 (ks1, CB0) ----
    load_bf<1, 0>(Pc, l, wc, bf);
    if (kt < 7) stage_q_half(qn, Qn, t, 1);
    LGKM0(); SCHEDBAR();
    mfma16<0>(af, bf, acc);
  }

  // Epilogue: two n-half sweeps; out = gse*D + bf16(x).
  float* Lf = (float*)lds;
  const unsigned short* xb = qbf + (size_t)b * C_ * N_;
  float* ob = out + (size_t)b * C_ * N_;
  const float* gseb = gse + b * C_;
  const int g16 = l >> 4;
#pragma unroll
  for (int s = 0; s < 2; ++s) {
    BARRAW();
    if (wn2 == s) {
#pragma unroll
      for (int nf = 0; nf < 8; ++nf)
#pragma unroll
        for (int j = 0; j < 4; ++j) {
          const int c_l = (j >> 1) * 128 + wc * 32 + (j & 1) * 16 + (l & 15);
          const int n4 = nf * 16 + g16 * 4;
          *(float4*)&Lf[c_l * 128 + (n4 ^ ((c_l & 7) << 2))] =
              *(const float4*)&acc[nf][j];
        }
    }
    BARRAW();
#pragma unroll
    for (int it = 0; it < 16; ++it) {
      const int row = it * 16 + (t >> 5);
      const int col4 = (t & 31) * 4;
      const int c = c0 + row;
      const float g = gseb[c];
      float4 v = *(const float4*)&Lf[row * 128 + (col4 ^ ((row & 7) << 2))];
      const size_t gofs = (size_t)c * N_ + n0 + s * 128 + col4;
      ushort4 xu = *(const ushort4*)(xb + gofs);
      float4 ov;
      ov.x = g * v.x + bf2f(xu.x);
      ov.y = g * v.y + bf2f(xu.y);
      ov.z = g * v.z + bf2f(xu.z);
      ov.w = g * v.w + bf2f(xu.w);
      *(float4*)(ob + gofs) = ov;
    }
  }
}

// ---------------------------------------------------------------- launch
extern "C" void kernel_launch(void* const* d_in, const int* in_sizes, int n_in,
                              void* d_out, int out_size, void* d_ws, size_t ws_size,
                              hipStream_t stream) {
  (void)in_sizes; (void)n_in; (void)out_size; (void)ws_size;
  const float* x     = (const float*)d_in[0];
  const float* gamma = (const float*)d_in[1];
  const float* W1    = (const float*)d_in[2];
  const float* b1    = (const float*)d_in[3];
  const float* W2    = (const float*)d_in[4];
  const float* b2    = (const float*)d_in[5];
  float* out = (float*)d_out;
  char* ws = (char*)d_ws;

  // ws: qbf bf16 64Mi | att bf16 8Mi | partial 32K | gse 32K  (~72.07 MiB)
  unsigned short* qbf     = (unsigned short*)(ws);
  unsigned short* att     = (unsigned short*)(ws + 67108864);
  float*          partial = (float*)(ws + 75497472);
  float*          gse     = (float*)(ws + 75530240);
  float* epartial = out;   // d_out[0:64Mi], k3 -> k4, dead before k5 writes out

  k1_convert<<<dim3(B_ * C_), dim3(256), 0, stream>>>(x, qbf, partial);
  k2_se<<<dim3(B_), dim3(256), 0, stream>>>(partial, gamma, W1, b1, W2, b2, gse);
  k3_energy<<<dim3(256), dim3(512), 0, stream>>>(qbf, epartial);
  k4_softmax<<<dim3(B_ * C_ / 4), dim3(256), 0, stream>>>(epartial, att);
  k5_pv<<<dim3(512), dim3(512), 0, stream>>>(att, qbf, gse, out);
}